// Round 1
// baseline (8312.086 us; speedup 1.0000x reference)
//
#include <hip/hip_runtime.h>
#include <hip/hip_bf16.h>

#define TLEN 512
#define BATCH 64
#define ISZ 256
#define HSZ 512
#define OSZ 256
#define G4 2048

typedef float f32x4 __attribute__((ext_vector_type(4)));
typedef short short8 __attribute__((ext_vector_type(8)));

#define MFMA(a, b, c) __builtin_amdgcn_mfma_f32_16x16x32_bf16((a), (b), (c), 0, 0, 0)

__device__ __forceinline__ unsigned short f2bf(float x) {
    unsigned int u = __float_as_uint(x);
    u = (u + 0x7fffu + ((u >> 16) & 1u)) >> 16;
    return (unsigned short)u;
}
__device__ __forceinline__ float bf2f(unsigned short h) {
    return __uint_as_float(((unsigned int)h) << 16);
}
__device__ __forceinline__ float sigmoidf_(float x) { return 1.0f / (1.0f + __expf(-x)); }
__device__ __forceinline__ float tanhf_(float x) { return 1.0f - 2.0f / (__expf(2.0f * x) + 1.0f); }

// ---------------- Phase A: x_gates = inputs @ W_ih^T + (b_ih + b_hh), bf16 out ---------------
__global__ void __launch_bounds__(512, 1) xg_gemm(
    const float* __restrict__ inp, const float* __restrict__ Wih,
    const float* __restrict__ b_ih, const float* __restrict__ b_hh,
    unsigned short* __restrict__ xg, int* __restrict__ slots)
{
    __shared__ short8 blds[8][8][64];   // [ntile][kf][lane], 64 KB
    const int tid = threadIdx.x;
    // re-zero barrier slots for the scan kernel (every launch)
    if (blockIdx.x == 0 && blockIdx.y == 0 && tid < 64) slots[tid * 32] = 0;
    {
        int row = tid >> 2;             // 0..127 within N-tile block
        int kseg = (tid & 3) * 64;
        int nt = row >> 4, nn = row & 15;
        const float* src = Wih + (size_t)(blockIdx.y * 128 + row) * ISZ + kseg;
        for (int kk = 0; kk < 64; ++kk) {
            int k = kseg + kk;
            int kf = k >> 5, sub = k & 31;
            ((unsigned short*)&blds[nt][kf][((sub >> 3) << 4) | nn])[sub & 7] = f2bf(src[kk]);
        }
    }
    __syncthreads();
    const int wave = tid >> 6, lane = tid & 63;
    const int m0 = blockIdx.x * 128 + wave * 16;
    f32x4 acc[8];
    #pragma unroll
    for (int i = 0; i < 8; ++i) acc[i] = (f32x4){0.f, 0.f, 0.f, 0.f};
    const float* arow = inp + (size_t)(m0 + (lane & 15)) * ISZ + ((lane >> 4) * 8);
    #pragma unroll
    for (int kf = 0; kf < 8; ++kf) {
        f32x4 a0 = *(const f32x4*)(arow + kf * 32);
        f32x4 a1 = *(const f32x4*)(arow + kf * 32 + 4);
        short8 af;
        #pragma unroll
        for (int i = 0; i < 4; ++i) { af[i] = (short)f2bf(a0[i]); af[4 + i] = (short)f2bf(a1[i]); }
        #pragma unroll
        for (int nt = 0; nt < 8; ++nt)
            acc[nt] = MFMA(af, blds[nt][kf][lane], acc[nt]);
    }
    const int nn = lane & 15;
    #pragma unroll
    for (int nt = 0; nt < 8; ++nt) {
        int nc = blockIdx.y * 128 + nt * 16 + nn;
        float bias = b_ih[nc] + b_hh[nc];
        #pragma unroll
        for (int r = 0; r < 4; ++r) {
            int m = m0 + (lane >> 4) * 4 + r;
            xg[(size_t)m * G4 + nc] = f2bf(acc[nt][r] + bias);
        }
    }
}

// ---------------- init-free global barrier (signed epochs; 0xAA poison < 0) ----------------
__device__ __forceinline__ void gbar(int* slots, int wg, int tid, int epoch) {
    __threadfence();
    __syncthreads();
    if (tid == 0)
        __hip_atomic_store(&slots[wg * 32], epoch, __ATOMIC_RELEASE, __HIP_MEMORY_SCOPE_AGENT);
    if (tid < 64) {
        while (__hip_atomic_load(&slots[tid * 32], __ATOMIC_ACQUIRE, __HIP_MEMORY_SCOPE_AGENT) < epoch) {}
    }
    __syncthreads();
}

// ---------------- Phase B: persistent sequential scan (cooperative, 64 WGs x 256) -----------
__global__ void __launch_bounds__(256, 1) lstm_scan(
    const float* __restrict__ Whh, const unsigned short* __restrict__ xg,
    unsigned short* __restrict__ hs, float* __restrict__ hbuf,
    int* __restrict__ slots, float* __restrict__ out_tail)
{
    // W_hh slice (32 gate rows x 512) as hi/lo bf16 planes, MFMA-B-frag layout. 64 KB.
    __shared__ short8 wlds[2][2][16][64];  // [plane][ntile][kf][lane]
    const int wg = blockIdx.x, tid = threadIdx.x;
    const int wave = tid >> 6, lane = tid & 63;
    {
        int rowi = tid >> 3;            // 0..31
        int kseg = (tid & 7) * 64;
        int nt = rowi >> 4, nin = rowi & 15;
        int gate = nt * 2 + (nin >> 3);            // ntile0=[i|f], ntile1=[g|o]
        int grow = gate * HSZ + wg * 8 + (nin & 7);
        const float* src = Whh + (size_t)grow * HSZ + kseg;
        for (int kk = 0; kk < 64; ++kk) {
            int k = kseg + kk;
            float v = src[kk];
            unsigned short hi = f2bf(v);
            unsigned short lo = f2bf(v - bf2f(hi));
            int kf = k >> 5, sub = k & 31;
            int lf = ((sub >> 3) << 4) | nin, e = sub & 7;
            ((unsigned short*)&wlds[0][nt][kf][lf])[e] = hi;
            ((unsigned short*)&wlds[1][nt][kf][lf])[e] = lo;
        }
    }
    {   // zero h_{-1} (parity-0 buffer), cooperatively across all 64 WGs
        int idx = (wg * 256 + tid) * 2;
        hbuf[idx] = 0.f; hbuf[idx + 1] = 0.f;
    }
    gbar(slots, wg, tid, 1);

    float c0 = 0.f, c1 = 0.f, c2 = 0.f, c3 = 0.f;   // c-state: lanes nn<8, 4 batches each
    const int nn = lane & 15;
    const int colj = wg * 8 + nn;                    // hidden column (valid for nn<8)

    for (int t = 0; t < TLEN; ++t) {
        const unsigned short* xg_t = xg + (size_t)t * (BATCH * G4);
        unsigned short xgv[4][4];
        if (nn < 8) {                                // prefetch x-gates early (independent of h)
            #pragma unroll
            for (int gi = 0; gi < 4; ++gi)
                #pragma unroll
                for (int r = 0; r < 4; ++r) {
                    int m = wave * 16 + ((lane >> 4) * 4) + r;
                    xgv[gi][r] = xg_t[(size_t)m * G4 + gi * HSZ + colj];
                }
        }
        const float* hb = hbuf + (t & 1) * (BATCH * HSZ);
        f32x4 acc0 = {0.f, 0.f, 0.f, 0.f}, acc1 = {0.f, 0.f, 0.f, 0.f};
        const float* hrow = hb + (wave * 16 + (lane & 15)) * HSZ + ((lane >> 4) * 8);
        #pragma unroll 4
        for (int kf = 0; kf < 16; ++kf) {
            f32x4 h0 = *(const f32x4*)(hrow + kf * 32);
            f32x4 h1 = *(const f32x4*)(hrow + kf * 32 + 4);
            short8 ahi, alo;
            #pragma unroll
            for (int i = 0; i < 4; ++i) {
                unsigned short q0 = f2bf(h0[i]);
                ahi[i] = (short)q0; alo[i] = (short)f2bf(h0[i] - bf2f(q0));
                unsigned short q1 = f2bf(h1[i]);
                ahi[4 + i] = (short)q1; alo[4 + i] = (short)f2bf(h1[i] - bf2f(q1));
            }
            short8 bh0 = wlds[0][0][kf][lane], bl0 = wlds[1][0][kf][lane];
            short8 bh1 = wlds[0][1][kf][lane], bl1 = wlds[1][1][kf][lane];
            acc0 = MFMA(ahi, bh0, acc0); acc0 = MFMA(ahi, bl0, acc0); acc0 = MFMA(alo, bh0, acc0);
            acc1 = MFMA(ahi, bh1, acc1); acc1 = MFMA(ahi, bl1, acc1); acc1 = MFMA(alo, bh1, acc1);
        }
        // f and o live 8 lanes over (cols 8..15); exchange with full wave active
        float fx[4], ox[4];
        #pragma unroll
        for (int r = 0; r < 4; ++r) { fx[r] = __shfl_xor(acc0[r], 8); ox[r] = __shfl_xor(acc1[r], 8); }
        float* hw = hbuf + ((t + 1) & 1) * (BATCH * HSZ);
        if (nn < 8) {
            float cr[4] = {c0, c1, c2, c3};
            #pragma unroll
            for (int r = 0; r < 4; ++r) {
                int m = wave * 16 + (lane >> 4) * 4 + r;
                float iv = acc0[r] + bf2f(xgv[0][r]);
                float fv = fx[r]   + bf2f(xgv[1][r]);
                float gv = acc1[r] + bf2f(xgv[2][r]);
                float ov = ox[r]   + bf2f(xgv[3][r]);
                float si = sigmoidf_(iv), sf = sigmoidf_(fv), so = sigmoidf_(ov);
                float tg = tanhf_(gv);
                float cn = sf * cr[r] + si * tg;
                cr[r] = cn;
                float hn = so * tanhf_(cn);
                hw[m * HSZ + colj] = hn;
                hs[((size_t)(t * BATCH + m)) * HSZ + colj] = f2bf(hn);
                if (t == TLEN - 1) {
                    out_tail[m * HSZ + colj] = hn;                 // h_T
                    out_tail[BATCH * HSZ + m * HSZ + colj] = cn;   // c_T
                }
            }
            c0 = cr[0]; c1 = cr[1]; c2 = cr[2]; c3 = cr[3];
        }
        gbar(slots, wg, tid, t + 2);
    }
}

// ---------------- Phase C: outputs = hs @ W_out^T + b_out (fp32 out) ------------------------
__global__ void __launch_bounds__(512, 1) out_gemm(
    const unsigned short* __restrict__ hs, const float* __restrict__ Wout,
    const float* __restrict__ b_out, float* __restrict__ out)
{
    __shared__ short8 blds[4][16][64];  // 64 KB
    const int tid = threadIdx.x;
    {
        int row = tid >> 3;             // 0..63
        int kseg = (tid & 7) * 64;
        int nt = row >> 4, nn = row & 15;
        const float* src = Wout + (size_t)(blockIdx.y * 64 + row) * HSZ + kseg;
        for (int kk = 0; kk < 64; ++kk) {
            int k = kseg + kk;
            int kf = k >> 5, sub = k & 31;
            ((unsigned short*)&blds[nt][kf][((sub >> 3) << 4) | nn])[sub & 7] = f2bf(src[kk]);
        }
    }
    __syncthreads();
    const int wave = tid >> 6, lane = tid & 63;
    const int m0 = blockIdx.x * 128 + wave * 16;
    f32x4 acc[4];
    #pragma unroll
    for (int i = 0; i < 4; ++i) acc[i] = (f32x4){0.f, 0.f, 0.f, 0.f};
    const unsigned short* arow = hs + (size_t)(m0 + (lane & 15)) * HSZ + ((lane >> 4) * 8);
    #pragma unroll
    for (int kf = 0; kf < 16; ++kf) {
        short8 a = *(const short8*)(arow + kf * 32);
        #pragma unroll
        for (int nt = 0; nt < 4; ++nt)
            acc[nt] = MFMA(a, blds[nt][kf][lane], acc[nt]);
    }
    const int nn = lane & 15;
    #pragma unroll
    for (int nt = 0; nt < 4; ++nt) {
        int nc = blockIdx.y * 64 + nt * 16 + nn;
        float bias = b_out[nc];
        #pragma unroll
        for (int r = 0; r < 4; ++r) {
            int m = m0 + (lane >> 4) * 4 + r;
            out[(size_t)m * OSZ + nc] = acc[nt][r] + bias;
        }
    }
}

extern "C" void kernel_launch(void* const* d_in, const int* in_sizes, int n_in,
                              void* d_out, int out_size, void* d_ws, size_t ws_size,
                              hipStream_t stream)
{
    const float* inputs = (const float*)d_in[0];  // [512,64,256]
    const float* W_ih  = (const float*)d_in[1];   // [2048,256]
    const float* W_hh  = (const float*)d_in[2];   // [2048,512]
    const float* b_ih  = (const float*)d_in[3];
    const float* b_hh  = (const float*)d_in[4];
    const float* W_out = (const float*)d_in[5];   // [256,512]
    const float* b_out = (const float*)d_in[6];
    float* out = (float*)d_out;

    char* ws = (char*)d_ws;
    unsigned short* xg = (unsigned short*)ws;                          // 134,217,728 B
    unsigned short* hs = (unsigned short*)(ws + 134217728);            //  33,554,432 B
    float* hbuf        = (float*)(ws + 134217728 + 33554432);          //     262,144 B
    int* slots         = (int*)(ws + 134217728 + 33554432 + 262144);   //       8,192 B

    xg_gemm<<<dim3(256, 16), 512, 0, stream>>>(inputs, W_ih, b_ih, b_hh, xg, slots);

    float* out_tail = out + (size_t)TLEN * BATCH * OSZ;
    const float* whh_p = W_hh;
    const unsigned short* xg_p = xg;
    unsigned short* hs_p = hs;
    float* hbuf_p = hbuf;
    int* slots_p = slots;
    float* tail_p = out_tail;
    void* scan_args[] = { &whh_p, &xg_p, &hs_p, &hbuf_p, &slots_p, &tail_p };
    hipLaunchCooperativeKernel((void*)lstm_scan, dim3(64), dim3(256), scan_args, 0, stream);

    out_gemm<<<dim3(256, 4), 512, 0, stream>>>(hs, W_out, b_out, out);
}

// Round 4
// 3660.529 us; speedup vs baseline: 2.2707x; 2.2707x over previous
//
#include <hip/hip_runtime.h>
#include <hip/hip_bf16.h>

#define TLEN 512
#define BATCH 64
#define ISZ 256
#define HSZ 512
#define OSZ 256
#define G4 2048

typedef float f32x4 __attribute__((ext_vector_type(4)));
typedef short short8 __attribute__((ext_vector_type(8)));
typedef int int4v __attribute__((ext_vector_type(4)));

#define MFMA(a, b, c) __builtin_amdgcn_mfma_f32_16x16x32_bf16((a), (b), (c), 0, 0, 0)

__device__ __forceinline__ unsigned short f2bf(float x) {
    unsigned int u = __float_as_uint(x);
    u = (u + 0x7fffu + ((u >> 16) & 1u)) >> 16;
    return (unsigned short)u;
}
__device__ __forceinline__ float bf2f(unsigned short h) {
    return __uint_as_float(((unsigned int)h) << 16);
}
__device__ __forceinline__ float sigmoidf_(float x) { return 1.0f / (1.0f + __expf(-x)); }
__device__ __forceinline__ float tanhf_(float x) { return 1.0f - 2.0f / (__expf(2.0f * x) + 1.0f); }

// ---------------- Phase A: x_gates = inputs @ W_ih^T + (b_ih + b_hh), bf16 out ---------------
__global__ void __launch_bounds__(512, 1) xg_gemm(
    const float* __restrict__ inp, const float* __restrict__ Wih,
    const float* __restrict__ b_ih, const float* __restrict__ b_hh,
    unsigned short* __restrict__ xg, int* __restrict__ flags)
{
    __shared__ short8 blds[8][8][64];   // [ntile][kf][lane], 64 KB
    const int tid = threadIdx.x;
    // re-zero flag slots for the scan kernel (every launch); agent-scope.
    if (blockIdx.x == 0 && blockIdx.y == 0)
        __hip_atomic_store(&flags[tid], 0, __ATOMIC_RELAXED, __HIP_MEMORY_SCOPE_AGENT);
    {
        int row = tid >> 2;             // 0..127 within N-tile block
        int kseg = (tid & 3) * 64;
        int nt = row >> 4, nn = row & 15;
        const float* src = Wih + (size_t)(blockIdx.y * 128 + row) * ISZ + kseg;
        for (int kk = 0; kk < 64; ++kk) {
            int k = kseg + kk;
            int kf = k >> 5, sub = k & 31;
            ((unsigned short*)&blds[nt][kf][((sub >> 3) << 4) | nn])[sub & 7] = f2bf(src[kk]);
        }
    }
    __syncthreads();
    const int wave = tid >> 6, lane = tid & 63;
    const int m0 = blockIdx.x * 128 + wave * 16;
    f32x4 acc[8];
    #pragma unroll
    for (int i = 0; i < 8; ++i) acc[i] = (f32x4){0.f, 0.f, 0.f, 0.f};
    const float* arow = inp + (size_t)(m0 + (lane & 15)) * ISZ + ((lane >> 4) * 8);
    #pragma unroll
    for (int kf = 0; kf < 8; ++kf) {
        f32x4 a0 = *(const f32x4*)(arow + kf * 32);
        f32x4 a1 = *(const f32x4*)(arow + kf * 32 + 4);
        short8 af;
        #pragma unroll
        for (int i = 0; i < 4; ++i) { af[i] = (short)f2bf(a0[i]); af[4 + i] = (short)f2bf(a1[i]); }
        #pragma unroll
        for (int nt = 0; nt < 8; ++nt)
            acc[nt] = MFMA(af, blds[nt][kf][lane], acc[nt]);
    }
    const int nn = lane & 15;
    #pragma unroll
    for (int nt = 0; nt < 8; ++nt) {
        int nc = blockIdx.y * 128 + nt * 16 + nn;
        float bias = b_ih[nc] + b_hh[nc];
        #pragma unroll
        for (int r = 0; r < 4; ++r) {
            int m = m0 + (lane >> 4) * 4 + r;
            xg[(size_t)m * G4 + nc] = f2bf(acc[nt][r] + bias);
        }
    }
}

// ---------------- Phase B: persistent scan, 32 WGs x 256, flag-pipelined LLC exchange -------
// Per WG: 16 hidden columns (all 4 gates). Per wave: 16 batch rows, independent end-to-end.
// W_hh bf16 in LDS (64 KB). h exchanged as hi/lo bf16 planes (recurrence ~fp32 precision):
// hbuf[parity][plane][64 rows][256 u32 col-pairs], agent-scope stores / sc0 sc1 loads.
// Sync per (wave,wg) flag: producer stores -> s_waitcnt vmcnt(0) -> flag; consumer polls
// flags >= t then loads. All waits are vmcnt(0) (robust to compiler-emitted VMEM/spills).
__global__ void __launch_bounds__(256, 1) lstm_scan(
    const float* __restrict__ Whh, const unsigned short* __restrict__ xg,
    unsigned short* __restrict__ hs, unsigned int* __restrict__ hbuf,
    int* __restrict__ flags, float* __restrict__ out_tail)
{
    __shared__ short8 wlds[4][16][64];   // [gate][kf][lane], 64 KB
    const int wg = blockIdx.x, tid = threadIdx.x;
    const int wave = tid >> 6, lane = tid & 63;
    const int l15 = lane & 15, l4 = lane >> 4;
    const int col = wg * 16 + l15;

    // wave g loads gate g's B-fragments: lane holds Whh[g*512 + wg*16 + (lane&15)][kf*32+(lane>>4)*8+e]
    {
        const int g = wave;
        const float* wrow = Whh + (size_t)(g * HSZ + wg * 16 + l15) * HSZ + l4 * 8;
        #pragma unroll
        for (int kf = 0; kf < 16; ++kf) {
            f32x4 w0 = *(const f32x4*)(wrow + kf * 32);
            f32x4 w1 = *(const f32x4*)(wrow + kf * 32 + 4);
            short8 f;
            #pragma unroll
            for (int e = 0; e < 4; ++e) { f[e] = (short)f2bf(w0[e]); f[4 + e] = (short)f2bf(w1[e]); }
            wlds[g][kf][lane] = f;
        }
    }
    __syncthreads();

    float cr[4] = {0.f, 0.f, 0.f, 0.f};
    const int mbase = wave * 16 + l4 * 4;

    #pragma unroll 1
    for (int t = 0; t < TLEN; ++t) {
        // ---- xg loads: plain cached, compiler-managed waits ----
        float xgf[4][4];
        #pragma unroll
        for (int r = 0; r < 4; ++r) {
            const unsigned short* xrow = xg + (size_t)(t * BATCH + mbase + r) * G4 + col;
            #pragma unroll
            for (int gi = 0; gi < 4; ++gi)
                xgf[gi][r] = bf2f(xrow[gi * HSZ]);
        }

        f32x4 acc[4];
        #pragma unroll
        for (int g = 0; g < 4; ++g) acc[g] = (f32x4){0.f, 0.f, 0.f, 0.f};

        if (t > 0) {
            // ---- poll the 32 producer flags of this wave's batch rows ----
            int fv;
            do {
                fv = (lane < 32)
                   ? __hip_atomic_load(&flags[(wave * 32 + lane) * 4], __ATOMIC_RELAXED, __HIP_MEMORY_SCOPE_AGENT)
                   : t;
            } while (__all(fv >= t) == 0);
            __builtin_amdgcn_sched_barrier(0);
            // ---- h fragment loads (hi/lo planes), LLC-coherent; ONE robust vmcnt(0) ----
            int4v hhi[16], hlo[16];
            const char* hb  = (const char*)hbuf + (t & 1) * 131072 + (size_t)(wave * 16 + l15) * 1024 + l4 * 16;
            const char* hbl = hb + 65536;
            #pragma unroll
            for (int kf = 0; kf < 16; ++kf) {
                asm volatile("global_load_dwordx4 %0, %1, off offset:%2 sc0 sc1"
                             : "=&v"(hhi[kf]) : "v"(hb),  "i"(kf * 64));
                asm volatile("global_load_dwordx4 %0, %1, off offset:%2 sc0 sc1"
                             : "=&v"(hlo[kf]) : "v"(hbl), "i"(kf * 64));
            }
            asm volatile("s_waitcnt vmcnt(0)" ::: "memory");
            __builtin_amdgcn_sched_barrier(0);
            #pragma unroll
            for (int kf = 0; kf < 16; ++kf) {
                short8 ah = *(short8*)&hhi[kf];
                short8 al = *(short8*)&hlo[kf];
                #pragma unroll
                for (int g = 0; g < 4; ++g) {
                    short8 b = wlds[g][kf][lane];
                    acc[g] = MFMA(ah, b, acc[g]);
                    acc[g] = MFMA(al, b, acc[g]);
                }
            }
        }

        // ---- gate math (fp32), c in registers ----
        float hnv[4];
        #pragma unroll
        for (int r = 0; r < 4; ++r) {
            float iv = acc[0][r] + xgf[0][r];
            float fv2= acc[1][r] + xgf[1][r];
            float gv = acc[2][r] + xgf[2][r];
            float ov = acc[3][r] + xgf[3][r];
            float si = sigmoidf_(iv), sf = sigmoidf_(fv2), so = sigmoidf_(ov);
            float tg = tanhf_(gv);
            float cn = sf * cr[r] + si * tg;
            cr[r] = cn;
            hnv[r] = so * tanhf_(cn);
        }

        // ---- publish h hi/lo planes (agent-scope) -> vmcnt(0) -> flag ----
        {
            const unsigned int pbase = (unsigned)(((t + 1) & 1) * 32768 + (l15 & 1) * 16384 + wg * 8 + (l15 >> 1));
            #pragma unroll
            for (int r = 0; r < 4; ++r) {
                unsigned int vh = f2bf(hnv[r]);
                unsigned int vl = f2bf(hnv[r] - bf2f((unsigned short)vh));
                unsigned int ph = (unsigned int)__shfl_xor((int)vh, 1);
                unsigned int pl = (unsigned int)__shfl_xor((int)vl, 1);
                unsigned int word = (l15 & 1) ? (pl | (vl << 16)) : (vh | (ph << 16));
                __hip_atomic_store(&hbuf[pbase + (unsigned)(mbase + r) * 256], word,
                                   __ATOMIC_RELAXED, __HIP_MEMORY_SCOPE_AGENT);
            }
        }
        asm volatile("s_waitcnt vmcnt(0)" ::: "memory");
        __builtin_amdgcn_sched_barrier(0);
        if (lane == 0)
            __hip_atomic_store(&flags[(wave * 32 + wg) * 4], t + 1, __ATOMIC_RELAXED, __HIP_MEMORY_SCOPE_AGENT);

        // ---- off-critical-path stores: hs history (+ tails at t==511), plain cached ----
        #pragma unroll
        for (int r = 0; r < 4; ++r) {
            int m = mbase + r;
            hs[((size_t)t * BATCH + m) * HSZ + col] = f2bf(hnv[r]);
            if (t == TLEN - 1) {
                out_tail[(size_t)m * HSZ + col] = hnv[r];                      // h_T
                out_tail[(size_t)BATCH * HSZ + (size_t)m * HSZ + col] = cr[r]; // c_T
            }
        }
    }
}

// ---------------- Phase C: outputs = hs @ W_out^T + b_out (fp32 out) ------------------------
__global__ void __launch_bounds__(512, 1) out_gemm(
    const unsigned short* __restrict__ hs, const float* __restrict__ Wout,
    const float* __restrict__ b_out, float* __restrict__ out)
{
    __shared__ short8 blds[4][16][64];  // 64 KB
    const int tid = threadIdx.x;
    {
        int row = tid >> 3;             // 0..63
        int kseg = (tid & 7) * 64;
        int nt = row >> 4, nn = row & 15;
        const float* src = Wout + (size_t)(blockIdx.y * 64 + row) * HSZ + kseg;
        for (int kk = 0; kk < 64; ++kk) {
            int k = kseg + kk;
            int kf = k >> 5, sub = k & 31;
            ((unsigned short*)&blds[nt][kf][((sub >> 3) << 4) | nn])[sub & 7] = f2bf(src[kk]);
        }
    }
    __syncthreads();
    const int wave = tid >> 6, lane = tid & 63;
    const int m0 = blockIdx.x * 128 + wave * 16;
    f32x4 acc[4];
    #pragma unroll
    for (int i = 0; i < 4; ++i) acc[i] = (f32x4){0.f, 0.f, 0.f, 0.f};
    const unsigned short* arow = hs + (size_t)(m0 + (lane & 15)) * HSZ + ((lane >> 4) * 8);
    #pragma unroll
    for (int kf = 0; kf < 16; ++kf) {
        short8 a = *(const short8*)(arow + kf * 32);
        #pragma unroll
        for (int nt = 0; nt < 4; ++nt)
            acc[nt] = MFMA(a, blds[nt][kf][lane], acc[nt]);
    }
    const int nn = lane & 15;
    #pragma unroll
    for (int nt = 0; nt < 4; ++nt) {
        int nc = blockIdx.y * 64 + nt * 16 + nn;
        float bias = b_out[nc];
        #pragma unroll
        for (int r = 0; r < 4; ++r) {
            int m = m0 + (lane >> 4) * 4 + r;
            out[(size_t)m * OSZ + nc] = acc[nt][r] + bias;
        }
    }
}

extern "C" void kernel_launch(void* const* d_in, const int* in_sizes, int n_in,
                              void* d_out, int out_size, void* d_ws, size_t ws_size,
                              hipStream_t stream)
{
    const float* inputs = (const float*)d_in[0];  // [512,64,256]
    const float* W_ih  = (const float*)d_in[1];   // [2048,256]
    const float* W_hh  = (const float*)d_in[2];   // [2048,512]
    const float* b_ih  = (const float*)d_in[3];
    const float* b_hh  = (const float*)d_in[4];
    const float* W_out = (const float*)d_in[5];   // [256,512]
    const float* b_out = (const float*)d_in[6];
    float* out = (float*)d_out;

    char* ws = (char*)d_ws;
    unsigned short* xg = (unsigned short*)ws;                              // 134,217,728 B
    unsigned short* hs = (unsigned short*)(ws + 134217728);                //  33,554,432 B
    unsigned int* hbuf = (unsigned int*)(ws + 134217728 + 33554432);       //     262,144 B
    int* flags         = (int*)(ws + 134217728 + 33554432 + 262144);       //       2,048 B

    xg_gemm<<<dim3(256, 16), 512, 0, stream>>>(inputs, W_ih, b_ih, b_hh, xg, flags);

    float* out_tail = out + (size_t)TLEN * BATCH * OSZ;
    const float* whh_p = W_hh;
    const unsigned short* xg_p = xg;
    unsigned short* hs_p = hs;
    unsigned int* hbuf_p = hbuf;
    int* flags_p = flags;
    float* tail_p = out_tail;
    void* scan_args[] = { &whh_p, &xg_p, &hs_p, &hbuf_p, &flags_p, &tail_p };
    hipLaunchCooperativeKernel((void*)lstm_scan, dim3(32), dim3(256), scan_args, 0, stream);

    out_gemm<<<dim3(256, 4), 512, 0, stream>>>(hs, W_out, b_out, out);
}